// Round 5
// baseline (395.499 us; speedup 1.0000x reference)
//
#include <hip/hip_runtime.h>

// CRF NLL: B=1024, S=512, T=48.
// R9: MFMA-batched chains.  R4-R8 proved the VALU chain-step (broadcast +
// 48-dot + cvt + republish) has an irreducible ~400ns serial latency and a
// hard 2-chain/SIMD overlap ceiling -> ~90us floor.  This kernel advances
// 16 chains per wave with 6 chained mfma_f32_16x16x32_f16 per step:
//   block = 2 waves over the same 16 batches.
//   wave0: forward alpha-chains (steps 1..nf), Op = E'.
//   wave1: backward beta-chains (steps len-1..nf+1), Op = E'^T.
// Step (uniform both directions): D-state (f32, D-layout: col=lane&15,
// row=(lane>>4)*4+reg [m89]) -> [B: *W] -> [rescale each 4th] -> clamp/cvt
// f16 -> LDS 16x48 -> read A-frags (row=lane&15, k=(lane>>4)*8+e, per
// m162's tr-read<->MFMA mapping) -> MFMA x6 (K=48 zero-padded to 64) ->
// [F: *W].  W = exp(em[pos]) applied in D-layout (12 values/lane),
// prefetched 2 steps ahead.  Chains snapshot their state+L at their own
// final step; Z = sum_j alpha_nf[j]*beta_nf[j] combined in-block via LDS.
// Numerics as proven: E' = exp(trans)*2^-8 f16, exact pow2 per-row rescale
// every 4 steps, 60000 clamp before every f16 convert.

#define T 48
#define SLEN 512
#define BATCH 1024
#define NB 16
#define NBLK (BATCH / NB)   // 64 blocks

typedef _Float16 f16x8 __attribute__((ext_vector_type(8)));
typedef float f32x4 __attribute__((ext_vector_type(4)));

__global__ __launch_bounds__(128) void crf_kernel(
    const float* __restrict__ em,      // (B,S,T)
    const int*   __restrict__ tags,    // (B,S)
    const float* __restrict__ mask,    // (B,S)
    const float* __restrict__ trans,   // (T,T)
    const float* __restrict__ start_t, // (T,)
    const float* __restrict__ end_t,   // (T,)
    float*       __restrict__ out)     // scalar
{
    constexpr float LOG2E = 1.4426950408889634f;
    constexpr float LN2   = 0.6931471805599453f;
    constexpr float ESC   = -8.0f;

    const int blk  = blockIdx.x;
    const int tid  = threadIdx.x;
    const int bwd  = tid >> 6;          // wave1 = backward chains
    const int lane = tid & 63;
    const int cl   = lane & 15;         // col-lane (j / k index)
    const int g    = lane >> 4;         // 4-lane-group

    __shared__ _Float16 trbuf[2][16 * 72];   // per-wave 16x48 (+pad to 72)
    __shared__ float    cmb[64][17];         // B-wave snap(12)+snapL(4), padded
    __shared__ float    meta[64];            // [0..15] len, [16..31] gold

    // zero transpose buffers (incl. k=48..71 pad read as MFMA zeros)
    for (int i = tid; i < 2 * 16 * 72; i += 128) trbuf[0][i] = (_Float16)0.f;

    // ---- lengths of the block's 16 batches ----
    {
        const float* mk = mask + (size_t)(blk * NB + cl) * SLEN;
        float ms = 0.f;
        #pragma unroll
        for (int k = 0; k < SLEN / 16; ++k) {
            const float4 v = *(const float4*)(mk + g * 4 + 16 * k);
            ms += (v.x + v.y) + (v.z + v.w);
        }
        ms += __shfl_xor(ms, 16, 64);
        ms += __shfl_xor(ms, 32, 64);
        if (tid < 16) meta[tid] = ms;   // wave0 lanes 0..15 publish len
    }
    __syncthreads();

    int len_[4], steps_[4];
    #pragma unroll
    for (int r = 0; r < 4; ++r) {
        const int L = (int)(meta[4 * g + r] + 0.5f);
        len_[r] = L;
        const int nbk = (L - 1) >> 1;
        const int nfk = (L - 1) - nbk;
        steps_[r] = bwd ? nbk : nfk;
    }

    // ---- E' operand fragments (constant, resident in VGPRs) ----
    // F: Op[k][j] = E'[k][j];  B: Op[j][k] = E'[k][j]  (E' = exp(trans)*2^-8)
    f16x8 Bop[3][2];
    #pragma unroll
    for (int t = 0; t < 3; ++t) {
        #pragma unroll
        for (int c = 0; c < 2; ++c) {
            f16x8 v;
            #pragma unroll
            for (int e = 0; e < 8; ++e) {
                const int kk = 32 * c + g * 8 + e;   // in-lane K index
                float tv;
                if (kk < T) {
                    const int idx = bwd ? (cl * T + kk)            // trans[k=cl][j=kk]
                                        : (kk * T + (cl + 16 * t)); // trans[k=kk][j]
                    tv = exp2f(trans[idx] * LOG2E + ESC);
                } else {
                    tv = 0.f;
                }
                v[e] = (_Float16)tv;
            }
            Bop[t][c] = v;
        }
    }
    // NOTE: for bwd, col = cl is the output index k and tile t enters via jj?
    // -> fix: bwd needs Op[jj][col], col = cl only spans 16; tiles select the
    // OUTPUT k-range, so bwd frag value is trans[(cl + 16*t... ) ] — see below.
    if (bwd) {
        #pragma unroll
        for (int t = 0; t < 3; ++t) {
            #pragma unroll
            for (int c = 0; c < 2; ++c) {
                f16x8 v;
                #pragma unroll
                for (int e = 0; e < 8; ++e) {
                    const int jj = 32 * c + g * 8 + e;       // contracted j
                    const int kout = cl + 16 * t;            // output k (N-dim)
                    v[e] = (jj < T)
                        ? (_Float16)exp2f(trans[kout * T + jj] * LOG2E + ESC)
                        : (_Float16)0.f;
                }
                Bop[t][c] = v;
            }
        }
    }

    // ---- per-row state init, W preloads (2 ahead) ----
    const float* bp[4];
    int noff[4];
    const int dstep = bwd ? -T : T;
    const int omax = (SLEN - 1) * T;
    float D[4][3], snap[4][3], Lr[4], snapL[4];
    float wA[4][3], wB[4][3];
    #pragma unroll
    for (int r = 0; r < 4; ++r) {
        bp[r] = em + (size_t)(blk * NB + 4 * g + r) * (SLEN * T);
        Lr[r] = 0.f;
        #pragma unroll
        for (int t = 0; t < 3; ++t) {
            const int ct = cl + 16 * t;
            D[r][t] = bwd ? exp2f(end_t[ct] * LOG2E)
                          : exp2f((start_t[ct] + bp[r][ct]) * LOG2E);
            snap[r][t] = D[r][t];          // rows with 0 steps keep init
        }
        snapL[r] = 0.f;
        int o0 = bwd ? (len_[r] - 1) * T : T;
        o0 = o0 < 0 ? 0 : (o0 > omax ? omax : o0);
        int o1 = o0 + dstep; o1 = o1 < 0 ? 0 : (o1 > omax ? omax : o1);
        int o2 = o1 + dstep; o2 = o2 < 0 ? 0 : (o2 > omax ? omax : o2);
        #pragma unroll
        for (int t = 0; t < 3; ++t) {
            wA[r][t] = bp[r][o0 + cl + 16 * t];
            wB[r][t] = bp[r][o1 + cl + 16 * t];
        }
        noff[r] = o2;
    }

    // wave-uniform max step count
    int mx = steps_[0];
    #pragma unroll
    for (int r = 1; r < 4; ++r) mx = steps_[r] > mx ? steps_[r] : mx;
    #pragma unroll
    for (int m = 1; m <= 32; m <<= 1) {
        const int o = __shfl_xor(mx, m, 64);
        mx = o > mx ? o : mx;
    }
    mx = __builtin_amdgcn_readfirstlane(mx);

    _Float16* myt = &trbuf[bwd][0];
    const int wr0 = 4 * g;                 // this lane's first D-row
    const int rd0 = cl * 72 + g * 8;       // A-frag chunk0 LDS offset

    auto body = [&](int s, float (&w)[4][3]) {
        // W = exp(em) for this step (loaded 2 steps ago)
        float wx[4][3];
        #pragma unroll
        for (int r = 0; r < 4; ++r)
            #pragma unroll
            for (int t = 0; t < 3; ++t)
                wx[r][t] = exp2f(w[r][t] * LOG2E);
        float Din[4][3];
        #pragma unroll
        for (int r = 0; r < 4; ++r)
            #pragma unroll
            for (int t = 0; t < 3; ++t)
                Din[r][t] = bwd ? D[r][t] * wx[r][t] : D[r][t];
        if ((s & 3) == 3) {                // exact pow2 per-row rescale
            #pragma unroll
            for (int r = 0; r < 4; ++r) {
                float m = fmaxf(fmaxf(Din[r][0], Din[r][1]), Din[r][2]);
                #pragma unroll
                for (int mm = 1; mm <= 8; mm <<= 1)
                    m = fmaxf(m, __shfl_xor(m, mm, 64));
                int e = ((__float_as_int(m) >> 23) & 255) - 127;
                e = e < -64 ? -64 : e;
                const float sc = __int_as_float((127 - e) << 23);
                #pragma unroll
                for (int t = 0; t < 3; ++t) Din[r][t] *= sc;
                Lr[r] += (float)e;
            }
        }
        // refill W ring for step s+2
        #pragma unroll
        for (int r = 0; r < 4; ++r) {
            #pragma unroll
            for (int t = 0; t < 3; ++t) w[r][t] = bp[r][noff[r] + cl + 16 * t];
            int nn = noff[r] + dstep;
            noff[r] = nn < 0 ? 0 : (nn > omax ? omax : nn);
        }
        // publish state: clamp, cvt f16, LDS (D-layout -> row-major 16x48)
        #pragma unroll
        for (int r = 0; r < 4; ++r)
            #pragma unroll
            for (int t = 0; t < 3; ++t)
                myt[(wr0 + r) * 72 + (cl + 16 * t)] =
                    (_Float16)fminf(Din[r][t], 60000.f);
        // A-frags (k 48..63 read the zeroed pad)
        const f16x8 A0 = *(const f16x8*)&myt[rd0];
        const f16x8 A1 = *(const f16x8*)&myt[rd0 + 32];
        f32x4 acc0 = {0.f, 0.f, 0.f, 0.f};
        f32x4 acc1 = {0.f, 0.f, 0.f, 0.f};
        f32x4 acc2 = {0.f, 0.f, 0.f, 0.f};
        acc0 = __builtin_amdgcn_mfma_f32_16x16x32_f16(A0, Bop[0][0], acc0, 0, 0, 0);
        acc1 = __builtin_amdgcn_mfma_f32_16x16x32_f16(A0, Bop[1][0], acc1, 0, 0, 0);
        acc2 = __builtin_amdgcn_mfma_f32_16x16x32_f16(A0, Bop[2][0], acc2, 0, 0, 0);
        acc0 = __builtin_amdgcn_mfma_f32_16x16x32_f16(A1, Bop[0][1], acc0, 0, 0, 0);
        acc1 = __builtin_amdgcn_mfma_f32_16x16x32_f16(A1, Bop[1][1], acc1, 0, 0, 0);
        acc2 = __builtin_amdgcn_mfma_f32_16x16x32_f16(A1, Bop[2][1], acc2, 0, 0, 0);
        // new state (+ F-side W), per-chain snapshot at its final step
        #pragma unroll
        for (int r = 0; r < 4; ++r) {
            float v0 = acc0[r], v1 = acc1[r], v2 = acc2[r];
            if (!bwd) { v0 *= wx[r][0]; v1 *= wx[r][1]; v2 *= wx[r][2]; }
            D[r][0] = v0; D[r][1] = v1; D[r][2] = v2;
            if (steps_[r] - 1 == s) {
                snap[r][0] = v0; snap[r][1] = v1; snap[r][2] = v2;
                snapL[r] = Lr[r];
            }
        }
    };

    for (int s = 0; s < mx; s += 2) {
        body(s, wA);
        body(s + 1, wB);      // harmless overrun when mx is odd
    }

    // ---- exchange + gold + combine ----
    if (bwd) {
        #pragma unroll
        for (int r = 0; r < 4; ++r) {
            #pragma unroll
            for (int t = 0; t < 3; ++t) cmb[lane][r * 3 + t] = snap[r][t];
            cmb[lane][12 + r] = snapL[r];
        }
    } else {
        // gold path score: 4 lanes per batch (batch = cl, positions 1+g step 4)
        const int bb = blk * NB + cl;
        const float* eb = em + (size_t)bb * (SLEN * T);
        const int* tb = tags + (size_t)bb * SLEN;
        const int Lb_ = (int)(meta[cl] + 0.5f);
        float gg = 0.f;
        for (int i = 1 + g; i < Lb_; i += 4) {
            const int tc = tb[i], tp = tb[i - 1];
            gg += trans[tc * T + tp] + eb[(size_t)i * T + tc];
        }
        if (g == 0) {
            const int t0 = tb[0], tl = tb[Lb_ - 1];
            gg += start_t[t0] + eb[t0] + end_t[tl];
        }
        gg += __shfl_xor(gg, 16, 64);
        gg += __shfl_xor(gg, 32, 64);
        if (g == 0) meta[16 + cl] = gg;
    }
    __syncthreads();

    if (!bwd) {
        float contrib = 0.f;
        #pragma unroll
        for (int r = 0; r < 4; ++r) {
            float v = snap[r][0] * cmb[lane][r * 3 + 0]
                    + snap[r][1] * cmb[lane][r * 3 + 1]
                    + snap[r][2] * cmb[lane][r * 3 + 2];
            #pragma unroll
            for (int mm = 1; mm <= 8; mm <<= 1) v += __shfl_xor(v, mm, 64);
            const int L = len_[r];
            const int nbk = (L - 1) >> 1;
            const int nfk = (L - 1) - nbk;
            const float fwd = (snapL[r] + cmb[lane][12 + r]
                               + 8.0f * (float)(nfk + nbk) + log2f(v)) * LN2;
            const float gold = meta[16 + 4 * g + r];
            contrib += (fwd - gold);
        }
        contrib *= (1.0f / (float)BATCH);
        contrib = (cl == 0) ? contrib : 0.f;   // one lane per 16-group counts
        #pragma unroll
        for (int m = 1; m <= 32; m <<= 1) contrib += __shfl_xor(contrib, m, 64);
        if (lane == 0) atomicAdd(out, contrib);
    }
}

extern "C" void kernel_launch(void* const* d_in, const int* in_sizes, int n_in,
                              void* d_out, int out_size, void* d_ws, size_t ws_size,
                              hipStream_t stream) {
    const float* em      = (const float*)d_in[0];
    const int*   tags    = (const int*)  d_in[1];
    const float* mask    = (const float*)d_in[2];
    const float* trans   = (const float*)d_in[3];
    const float* start_t = (const float*)d_in[4];
    const float* end_t   = (const float*)d_in[5];
    float* out = (float*)d_out;

    hipMemsetAsync(out, 0, sizeof(float), stream);
    crf_kernel<<<NBLK, 128, 0, stream>>>(em, tags, mask, trans, start_t, end_t, out);
}